// Round 4
// baseline (402.969 us; speedup 1.0000x reference)
//
#include <hip/hip_runtime.h>
#include <hip/hip_bf16.h>

using bf16 = __hip_bfloat16;

#define K 25
#define B 256
#define NBLK 512   // grid size; __launch_bounds__(256,2) guarantees 2 blocks/CU
                   // on 256 CUs -> all 512 blocks co-resident -> sw barrier safe

__device__ __forceinline__ float b2f(ushort u) {
  unsigned int w = ((unsigned int)u) << 16;
  float f; __builtin_memcpy(&f, &w, 4); return f;
}
__device__ __forceinline__ ushort f2b(float f) {
  bf16 h = __float2bfloat16(f);
  ushort u; __builtin_memcpy(&u, &h, 2); return u;
}

struct Params {
  const void *x, *knn0, *knn1, *knn2;
  const void *wp0, *bp0, *wp1, *bp1, *wp2, *bp2, *fcpw, *fcpb;
  const void *wn0, *bn0, *wn1, *bn1, *wn2, *bn2, *fcnw, *fcnb;
  const void *f3w, *f3b;
  ushort *xT, *h0, *h1, *h2;
  float *y;
  int *bars;       // 5 counters, 64 B apart, zeroed by memset each call
  void *out;
};

// Grid barrier: release-fence, count, spin, acquire-fence.
__device__ __forceinline__ void gbar(int* bars, int idx) {
  __syncthreads();
  if (threadIdx.x == 0) {
    __threadfence();                       // flush our stores (device scope)
    atomicAdd(&bars[idx * 16], 1);
    while (atomicAdd(&bars[idx * 16], 0) < NBLK) {
      __builtin_amdgcn_s_sleep(2);
    }
    __threadfence();                       // invalidate stale cached lines
  }
  __syncthreads();
}

__device__ __forceinline__ void lcn_stage(const ushort* __restrict__ inT,
                                          const void* __restrict__ knn,
                                          const void* wP, const void* bP,
                                          const void* wN, const void* bN,
                                          ushort* __restrict__ outT,
                                          int prev, int dout, int fdt, int idt) {
  const int wave = threadIdx.x >> 6;
  const int lane = threadIdx.x & 63;
  for (int wt = (blockIdx.x << 2) | wave; wt < 2 * dout; wt += NBLK * 4) {
    const int ch = wt >= dout;
    const int d = ch ? wt - dout : wt;
    const ushort* in = inT + (size_t)ch * prev * B;
    const void* wsel = ch ? wN : wP;
    const void* bsel = ch ? bN : bP;

    int r[K]; float wk[K];
    if (idt) {
      const long long* ip = (const long long*)knn + (size_t)d * K;
#pragma unroll
      for (int k = 0; k < K; ++k) r[k] = (int)ip[k];
    } else {
      const int* ip = (const int*)knn + (size_t)d * K;
#pragma unroll
      for (int k = 0; k < K; ++k) r[k] = ip[k];
    }
    if (fdt) {
      const ushort* wp = (const ushort*)wsel + (size_t)d * K;
#pragma unroll
      for (int k = 0; k < K; ++k) wk[k] = b2f(wp[k]);
    } else {
      const float* wp = (const float*)wsel + (size_t)d * K;
#pragma unroll
      for (int k = 0; k < K; ++k) wk[k] = wp[k];
    }
    const float bias = fdt ? b2f(((const ushort*)bsel)[d]) : ((const float*)bsel)[d];

    float a0 = 0.f, a1 = 0.f, a2 = 0.f, a3 = 0.f;
#pragma unroll
    for (int k = 0; k < K; ++k) {
      const ushort4 v = *(const ushort4*)(in + (size_t)r[k] * B + (lane << 2));
      a0 = fmaf(wk[k], b2f(v.x), a0);
      a1 = fmaf(wk[k], b2f(v.y), a1);
      a2 = fmaf(wk[k], b2f(v.z), a2);
      a3 = fmaf(wk[k], b2f(v.w), a3);
    }
    a0 = fmaxf(a0 + bias, 0.f);
    a1 = fmaxf(a1 + bias, 0.f);
    a2 = fmaxf(a2 + bias, 0.f);
    a3 = fmaxf(a3 + bias, 0.f);
    ushort4 o; o.x = f2b(a0); o.y = f2b(a1); o.z = f2b(a2); o.w = f2b(a3);
    *(ushort4*)(outT + ((size_t)ch * dout + d) * B + (lane << 2)) = o;
  }
}

__global__ __launch_bounds__(256, 2) void fused_kernel(Params p) {
  __shared__ float tile[64][65];

  // ---- inline dtype detection (identical logic to validated detect_kernel) ----
  int fdt, idt;
  {
    const unsigned int* xw = (const unsigned int*)p.x;
    int weird = 0;
    for (int i = 0; i < 64; ++i) {
      unsigned int e = (xw[i * 997] >> 23) & 0xFF;
      weird += (e >= 192) || (e <= 30);
    }
    fdt = (weird >= 32);
    const unsigned int* kw = (const unsigned int*)p.knn0;
    int nz = 0;
    for (int i = 0; i < 64; ++i) nz += (kw[2 * i + 1] != 0);
    idt = (nz == 0);
  }

  // ---- stage A: transpose x (256 x 28800) -> xT (28800 x 256 bf16) ----
  const int t0 = threadIdx.x;
  for (int t = blockIdx.x; t < 1800; t += NBLK) {
    const int f0 = (t % 450) * 64;
    const int b0 = (t / 450) * 64;
    if (!fdt) {
      const float* xp = (const float*)p.x;
#pragma unroll
      for (int q = 0; q < 4; ++q) {
        const int lin = t0 + q * 256;
        const int bl = lin >> 4;
        const int fq = (lin & 15) << 2;
        const float4 v = *(const float4*)(xp + (size_t)(b0 + bl) * 28800 + f0 + fq);
        tile[bl][fq] = v.x; tile[bl][fq + 1] = v.y;
        tile[bl][fq + 2] = v.z; tile[bl][fq + 3] = v.w;
      }
    } else {
      const ushort* xp = (const ushort*)p.x;
#pragma unroll
      for (int q = 0; q < 4; ++q) {
        const int lin = t0 + q * 256;
        const int bl = lin >> 4;
        const int fq = (lin & 15) << 2;
        const ushort4 v = *(const ushort4*)(xp + (size_t)(b0 + bl) * 28800 + f0 + fq);
        tile[bl][fq] = b2f(v.x); tile[bl][fq + 1] = b2f(v.y);
        tile[bl][fq + 2] = b2f(v.z); tile[bl][fq + 3] = b2f(v.w);
      }
    }
    __syncthreads();
#pragma unroll
    for (int q = 0; q < 4; ++q) {
      const int lin = t0 + q * 256;
      const int fl = lin >> 4;
      const int bq = (lin & 15) << 2;
      ushort4 o;
      o.x = f2b(tile[bq][fl]);     o.y = f2b(tile[bq + 1][fl]);
      o.z = f2b(tile[bq + 2][fl]); o.w = f2b(tile[bq + 3][fl]);
      *(ushort4*)(p.xT + (size_t)(f0 + fl) * B + b0 + bq) = o;
    }
    __syncthreads();
  }
  gbar(p.bars, 0);

  // ---- stages B: the three LCN layers ----
  lcn_stage(p.xT, p.knn0, p.wp0, p.bp0, p.wn0, p.bn0, p.h0, 14400, 7200, fdt, idt);
  gbar(p.bars, 1);
  lcn_stage(p.h0, p.knn1, p.wp1, p.bp1, p.wn1, p.bn1, p.h1, 7200, 3600, fdt, idt);
  gbar(p.bars, 2);
  lcn_stage(p.h1, p.knn2, p.wp2, p.bp2, p.wn2, p.bn2, p.h2, 3600, 1800, fdt, idt);
  gbar(p.bars, 3);

  // ---- stage C: per-channel fc (wave-tasked, atomics into zeroed y) ----
  {
    const int wave = threadIdx.x >> 6;
    const int lane = threadIdx.x & 63;
    for (int wt = (blockIdx.x << 2) | wave; wt < 450; wt += NBLK * 4) {
      const int ch = wt >= 225;
      const int c0 = (ch ? wt - 225 : wt) * 8;
      const ushort* h = p.h2 + (size_t)ch * 1800 * B;
      const void* fw = ch ? p.fcnw : p.fcpw;
      float w0[8], w1[8];
      if (fdt) {
        const ushort* fp = (const ushort*)fw;
#pragma unroll
        for (int j = 0; j < 8; ++j) { w0[j] = b2f(fp[c0 + j]); w1[j] = b2f(fp[1800 + c0 + j]); }
      } else {
        const float* fp = (const float*)fw;
#pragma unroll
        for (int j = 0; j < 8; ++j) { w0[j] = fp[c0 + j]; w1[j] = fp[1800 + c0 + j]; }
      }
      float s0[4] = {0.f, 0.f, 0.f, 0.f}, s1[4] = {0.f, 0.f, 0.f, 0.f};
#pragma unroll
      for (int j = 0; j < 8; ++j) {
        const ushort4 v = *(const ushort4*)(h + (size_t)(c0 + j) * B + (lane << 2));
        const float f0v = b2f(v.x), f1v = b2f(v.y), f2v = b2f(v.z), f3v = b2f(v.w);
        s0[0] = fmaf(w0[j], f0v, s0[0]); s0[1] = fmaf(w0[j], f1v, s0[1]);
        s0[2] = fmaf(w0[j], f2v, s0[2]); s0[3] = fmaf(w0[j], f3v, s0[3]);
        s1[0] = fmaf(w1[j], f0v, s1[0]); s1[1] = fmaf(w1[j], f1v, s1[1]);
        s1[2] = fmaf(w1[j], f2v, s1[2]); s1[3] = fmaf(w1[j], f3v, s1[3]);
      }
#pragma unroll
      for (int i = 0; i < 4; ++i) {
        atomicAdd(&p.y[(ch * 2 + 0) * B + (lane << 2) + i], s0[i]);
        atomicAdd(&p.y[(ch * 2 + 1) * B + (lane << 2) + i], s1[i]);
      }
    }
  }
  gbar(p.bars, 4);

  // ---- stage D: combine + output (block 0 only) ----
  if (blockIdx.x == 0) {
    const int b = threadIdx.x;
    const float bp0v = fdt ? b2f(((const ushort*)p.fcpb)[0]) : ((const float*)p.fcpb)[0];
    const float bp1v = fdt ? b2f(((const ushort*)p.fcpb)[1]) : ((const float*)p.fcpb)[1];
    const float bn0v = fdt ? b2f(((const ushort*)p.fcnb)[0]) : ((const float*)p.fcnb)[0];
    const float bn1v = fdt ? b2f(((const ushort*)p.fcnb)[1]) : ((const float*)p.fcnb)[1];
    const float h0v = fmaxf(p.y[0 * B + b] + bp0v, 0.f);
    const float h1v = fmaxf(p.y[1 * B + b] + bp1v, 0.f);
    const float h2v = fmaxf(p.y[2 * B + b] + bn0v, 0.f);
    const float h3v = fmaxf(p.y[3 * B + b] + bn1v, 0.f);
#pragma unroll
    for (int o = 0; o < 2; ++o) {
      float w0, w1, w2, w3, bb;
      if (fdt) {
        const ushort* fp = (const ushort*)p.f3w;
        w0 = b2f(fp[o * 4 + 0]); w1 = b2f(fp[o * 4 + 1]);
        w2 = b2f(fp[o * 4 + 2]); w3 = b2f(fp[o * 4 + 3]);
        bb = b2f(((const ushort*)p.f3b)[o]);
      } else {
        const float* fp = (const float*)p.f3w;
        w0 = fp[o * 4 + 0]; w1 = fp[o * 4 + 1];
        w2 = fp[o * 4 + 2]; w3 = fp[o * 4 + 3];
        bb = ((const float*)p.f3b)[o];
      }
      float r = bb;
      r = fmaf(w0, h0v, r); r = fmaf(w1, h1v, r);
      r = fmaf(w2, h2v, r); r = fmaf(w3, h3v, r);
      if (fdt) ((ushort*)p.out)[b * 2 + o] = f2b(r);
      else     ((float*)p.out)[b * 2 + o] = r;
    }
  }
}

extern "C" void kernel_launch(void* const* d_in, const int* in_sizes, int n_in,
                              void* d_out, int out_size, void* d_ws, size_t ws_size,
                              hipStream_t stream) {
  char* ws = (char*)d_ws;
  Params p;
  p.x    = d_in[0];
  p.knn0 = d_in[1];  p.knn1 = d_in[2];  p.knn2 = d_in[3];
  p.wp0  = d_in[4];  p.bp0  = d_in[5];
  p.wp1  = d_in[6];  p.bp1  = d_in[7];
  p.wp2  = d_in[8];  p.bp2  = d_in[9];
  p.fcpw = d_in[10]; p.fcpb = d_in[11];
  p.wn0  = d_in[12]; p.bn0  = d_in[13];
  p.wn1  = d_in[14]; p.bn1  = d_in[15];
  p.wn2  = d_in[16]; p.bn2  = d_in[17];
  p.fcnw = d_in[18]; p.fcnb = d_in[19];
  p.f3w  = d_in[20]; p.f3b  = d_in[21];

  p.xT   = (ushort*)(ws);                 // 28800*256*2 = 14,745,600 B
  p.h0   = (ushort*)(ws + 14745600);      //  2*7200*256*2 = 7,372,800 B
  p.h1   = (ushort*)(ws + 22118400);      //  2*3600*256*2 = 3,686,400 B
  p.h2   = (ushort*)(ws + 25804800);      //  2*1800*256*2 = 1,843,200 B
  p.y    = (float*)(ws + 27648000);       //  4*256*4 = 4,096 B
  p.bars = (int*)(ws + 27652096);         //  5*64 = 320 B
  p.out  = d_out;

  // zero y accumulators + barrier counters (ws is poisoned 0xAA before each call)
  hipMemsetAsync(ws + 27648000, 0, 8192, stream);

  fused_kernel<<<NBLK, 256, 0, stream>>>(p);
}

// Round 5
// 181.173 us; speedup vs baseline: 2.2242x; 2.2242x over previous
//
#include <hip/hip_runtime.h>
#include <hip/hip_bf16.h>

using bf16 = __hip_bfloat16;

#define K 25
#define B 256

__device__ __forceinline__ float b2f(ushort u) {
  unsigned int w = ((unsigned int)u) << 16;
  float f; __builtin_memcpy(&f, &w, 4); return f;
}
__device__ __forceinline__ ushort f2b(float f) {
  bf16 h = __float2bfloat16(f);
  ushort u; __builtin_memcpy(&u, &h, 2); return u;
}

// ---------------------------------------------------------------------------
// Dtype detection (validated in rounds 2-4).
// fdt=1 -> float tensors bf16, 0 -> fp32. idt=1 -> knn int64, 0 -> int32.
// ---------------------------------------------------------------------------
__device__ __forceinline__ int detect_fdt(const void* x) {
  const unsigned int* xw = (const unsigned int*)x;
  int weird = 0;
  for (int i = 0; i < 64; ++i) {
    unsigned int e = (xw[i * 997] >> 23) & 0xFF;
    weird += (e >= 192) || (e <= 30);
  }
  return (weird >= 32) ? 1 : 0;
}
__device__ __forceinline__ int detect_idt(const void* knn0) {
  const unsigned int* kw = (const unsigned int*)knn0;
  int nz = 0;
  for (int i = 0; i < 64; ++i) nz += (kw[2 * i + 1] != 0);
  return (nz == 0) ? 1 : 0;
}

// ---------------------------------------------------------------------------
// Transpose x (256 x 28800) -> xT (28800 x 256 bf16), 64x64 tiles, vectorized.
// grid (450, 4). Block (0,0) additionally: writes flags, zeros y + done ctr.
// ---------------------------------------------------------------------------
__global__ __launch_bounds__(256) void transpose_kernel(const void* __restrict__ x,
                                                        const void* __restrict__ knn0,
                                                        ushort* __restrict__ xT,
                                                        float* __restrict__ y,
                                                        int* __restrict__ flags) {
  __shared__ float tile[64][65];
  __shared__ int s_fdt;
  const int t = threadIdx.x;
  if (t == 0) s_fdt = detect_fdt(x);
  __syncthreads();
  const int fdt = s_fdt;

  if (blockIdx.x == 0 && blockIdx.y == 0) {
    // publish flags for downstream kernels; zero fc accumulators + done ctr
    if (t == 0) {
      flags[0] = fdt;
      flags[1] = detect_idt(knn0);
      flags[16] = 0;                       // fc done-counter (separate line)
    }
#pragma unroll
    for (int i = 0; i < 4; ++i) y[t + i * 256] = 0.0f;
  }

  const int f0 = blockIdx.x * 64;
  const int b0 = blockIdx.y * 64;
  if (fdt) {
    const ushort* xp = (const ushort*)x;
#pragma unroll
    for (int q = 0; q < 4; ++q) {
      const int lin = t + q * 256;
      const int bl = lin >> 4;
      const int fq = (lin & 15) << 2;
      const ushort4 v = *(const ushort4*)(xp + (size_t)(b0 + bl) * 28800 + f0 + fq);
      tile[bl][fq] = b2f(v.x); tile[bl][fq + 1] = b2f(v.y);
      tile[bl][fq + 2] = b2f(v.z); tile[bl][fq + 3] = b2f(v.w);
    }
  } else {
    const float* xp = (const float*)x;
#pragma unroll
    for (int q = 0; q < 4; ++q) {
      const int lin = t + q * 256;
      const int bl = lin >> 4;
      const int fq = (lin & 15) << 2;
      const float4 v = *(const float4*)(xp + (size_t)(b0 + bl) * 28800 + f0 + fq);
      tile[bl][fq] = v.x; tile[bl][fq + 1] = v.y;
      tile[bl][fq + 2] = v.z; tile[bl][fq + 3] = v.w;
    }
  }
  __syncthreads();
#pragma unroll
  for (int q = 0; q < 4; ++q) {
    const int lin = t + q * 256;
    const int fl = lin >> 4;
    const int bq = (lin & 15) << 2;
    ushort4 o;
    o.x = f2b(tile[bq][fl]);     o.y = f2b(tile[bq + 1][fl]);
    o.z = f2b(tile[bq + 2][fl]); o.w = f2b(tile[bq + 3][fl]);
    *(ushort4*)(xT + (size_t)(f0 + fl) * B + b0 + bq) = o;
  }
}

// ---------------------------------------------------------------------------
// One LCN layer, both channels. One wave per output dim; lane covers 4 batch
// elems (ushort4 = one 512 B row per wave). grid (dout/4, 2).
// ---------------------------------------------------------------------------
__global__ __launch_bounds__(256) void lcn_layer(const ushort* __restrict__ inT,
                                                 const void* __restrict__ knn,
                                                 const void* __restrict__ wp,
                                                 const void* __restrict__ bp,
                                                 const void* __restrict__ wn,
                                                 const void* __restrict__ bn,
                                                 ushort* __restrict__ outT,
                                                 const int* __restrict__ flags,
                                                 int prev, int dout) {
  const int fdt = flags[0];
  const int idt = flags[1];
  const int wave = threadIdx.x >> 6;
  const int lane = threadIdx.x & 63;
  const int d = blockIdx.x * 4 + wave;
  const int ch = blockIdx.y;
  const ushort* in = inT + (size_t)ch * prev * B;
  const void* wsel = ch ? wn : wp;
  const void* bsel = ch ? bn : bp;

  int r[K]; float wk[K];
  if (idt) {
    const long long* ip = (const long long*)knn + (size_t)d * K;
#pragma unroll
    for (int k = 0; k < K; ++k) r[k] = (int)ip[k];
  } else {
    const int* ip = (const int*)knn + (size_t)d * K;
#pragma unroll
    for (int k = 0; k < K; ++k) r[k] = ip[k];
  }
  if (fdt) {
    const ushort* wpp = (const ushort*)wsel + (size_t)d * K;
#pragma unroll
    for (int k = 0; k < K; ++k) wk[k] = b2f(wpp[k]);
  } else {
    const float* wpp = (const float*)wsel + (size_t)d * K;
#pragma unroll
    for (int k = 0; k < K; ++k) wk[k] = wpp[k];
  }
  const float bias = fdt ? b2f(((const ushort*)bsel)[d]) : ((const float*)bsel)[d];

  float a0 = 0.f, a1 = 0.f, a2 = 0.f, a3 = 0.f;
#pragma unroll
  for (int k = 0; k < K; ++k) {
    const ushort4 v = *(const ushort4*)(in + (size_t)r[k] * B + (lane << 2));
    a0 = fmaf(wk[k], b2f(v.x), a0);
    a1 = fmaf(wk[k], b2f(v.y), a1);
    a2 = fmaf(wk[k], b2f(v.z), a2);
    a3 = fmaf(wk[k], b2f(v.w), a3);
  }
  a0 = fmaxf(a0 + bias, 0.f);
  a1 = fmaxf(a1 + bias, 0.f);
  a2 = fmaxf(a2 + bias, 0.f);
  a3 = fmaxf(a3 + bias, 0.f);
  ushort4 o; o.x = f2b(a0); o.y = f2b(a1); o.z = f2b(a2); o.w = f2b(a3);
  *(ushort4*)(outT + ((size_t)ch * dout + d) * B + (lane << 2)) = o;
}

// ---------------------------------------------------------------------------
// fc (wave-tasked, atomics into zeroed y) + fused final combine (last block).
// grid 113 blocks x 256. 450 wave-tasks of 8 dims each.
// ---------------------------------------------------------------------------
__global__ __launch_bounds__(256) void fc_final_kernel(const ushort* __restrict__ h2,
                                                       const void* __restrict__ fcpw,
                                                       const void* __restrict__ fcnw,
                                                       const void* __restrict__ fcpb,
                                                       const void* __restrict__ fcnb,
                                                       const void* __restrict__ f3w,
                                                       const void* __restrict__ f3b,
                                                       float* __restrict__ y,
                                                       int* __restrict__ flags,
                                                       void* __restrict__ out) {
  const int fdt = flags[0];
  const int wave = threadIdx.x >> 6;
  const int lane = threadIdx.x & 63;
  const int wt = blockIdx.x * 4 + wave;
  __shared__ int s_last;

  if (wt < 450) {
    const int ch = wt >= 225;
    const int c0 = (ch ? wt - 225 : wt) * 8;
    const ushort* h = h2 + (size_t)ch * 1800 * B;
    const void* fw = ch ? fcnw : fcpw;
    float w0[8], w1[8];
    if (fdt) {
      const ushort* fp = (const ushort*)fw;
#pragma unroll
      for (int j = 0; j < 8; ++j) { w0[j] = b2f(fp[c0 + j]); w1[j] = b2f(fp[1800 + c0 + j]); }
    } else {
      const float* fp = (const float*)fw;
#pragma unroll
      for (int j = 0; j < 8; ++j) { w0[j] = fp[c0 + j]; w1[j] = fp[1800 + c0 + j]; }
    }
    float s0[4] = {0.f, 0.f, 0.f, 0.f}, s1[4] = {0.f, 0.f, 0.f, 0.f};
#pragma unroll
    for (int j = 0; j < 8; ++j) {
      const ushort4 v = *(const ushort4*)(h + (size_t)(c0 + j) * B + (lane << 2));
      const float f0v = b2f(v.x), f1v = b2f(v.y), f2v = b2f(v.z), f3v = b2f(v.w);
      s0[0] = fmaf(w0[j], f0v, s0[0]); s0[1] = fmaf(w0[j], f1v, s0[1]);
      s0[2] = fmaf(w0[j], f2v, s0[2]); s0[3] = fmaf(w0[j], f3v, s0[3]);
      s1[0] = fmaf(w1[j], f0v, s1[0]); s1[1] = fmaf(w1[j], f1v, s1[1]);
      s1[2] = fmaf(w1[j], f2v, s1[2]); s1[3] = fmaf(w1[j], f3v, s1[3]);
    }
#pragma unroll
    for (int i = 0; i < 4; ++i) {
      atomicAdd(&y[(ch * 2 + 0) * B + (lane << 2) + i], s0[i]);
      atomicAdd(&y[(ch * 2 + 1) * B + (lane << 2) + i], s1[i]);
    }
  }

  // last-block-does-final: no residency assumption, device-scope atomics
  __syncthreads();
  if (threadIdx.x == 0) {
    __threadfence();
    s_last = (atomicAdd(&flags[16], 1) == gridDim.x - 1);
  }
  __syncthreads();
  if (s_last) {
    const int b = threadIdx.x;
    // read y through atomics (same coherence point as the producers)
    const float y0 = atomicAdd(&y[0 * B + b], 0.0f);
    const float y1 = atomicAdd(&y[1 * B + b], 0.0f);
    const float y2 = atomicAdd(&y[2 * B + b], 0.0f);
    const float y3 = atomicAdd(&y[3 * B + b], 0.0f);
    const float bp0v = fdt ? b2f(((const ushort*)fcpb)[0]) : ((const float*)fcpb)[0];
    const float bp1v = fdt ? b2f(((const ushort*)fcpb)[1]) : ((const float*)fcpb)[1];
    const float bn0v = fdt ? b2f(((const ushort*)fcnb)[0]) : ((const float*)fcnb)[0];
    const float bn1v = fdt ? b2f(((const ushort*)fcnb)[1]) : ((const float*)fcnb)[1];
    const float h0v = fmaxf(y0 + bp0v, 0.f);
    const float h1v = fmaxf(y1 + bp1v, 0.f);
    const float h2v = fmaxf(y2 + bn0v, 0.f);
    const float h3v = fmaxf(y3 + bn1v, 0.f);
#pragma unroll
    for (int o = 0; o < 2; ++o) {
      float w0, w1, w2, w3, bb;
      if (fdt) {
        const ushort* fp = (const ushort*)f3w;
        w0 = b2f(fp[o * 4 + 0]); w1 = b2f(fp[o * 4 + 1]);
        w2 = b2f(fp[o * 4 + 2]); w3 = b2f(fp[o * 4 + 3]);
        bb = b2f(((const ushort*)f3b)[o]);
      } else {
        const float* fp = (const float*)f3w;
        w0 = fp[o * 4 + 0]; w1 = fp[o * 4 + 1];
        w2 = fp[o * 4 + 2]; w3 = fp[o * 4 + 3];
        bb = ((const float*)f3b)[o];
      }
      float r = bb;
      r = fmaf(w0, h0v, r); r = fmaf(w1, h1v, r);
      r = fmaf(w2, h2v, r); r = fmaf(w3, h3v, r);
      if (fdt) ((ushort*)out)[b * 2 + o] = f2b(r);
      else     ((float*)out)[b * 2 + o] = r;
    }
  }
}

extern "C" void kernel_launch(void* const* d_in, const int* in_sizes, int n_in,
                              void* d_out, int out_size, void* d_ws, size_t ws_size,
                              hipStream_t stream) {
  const void* x    = d_in[0];
  const void* knn0 = d_in[1];
  const void* knn1 = d_in[2];
  const void* knn2 = d_in[3];
  const void* wp0  = d_in[4];  const void* bp0 = d_in[5];
  const void* wp1  = d_in[6];  const void* bp1 = d_in[7];
  const void* wp2  = d_in[8];  const void* bp2 = d_in[9];
  const void* fcpw = d_in[10]; const void* fcpb = d_in[11];
  const void* wn0  = d_in[12]; const void* bn0 = d_in[13];
  const void* wn1  = d_in[14]; const void* bn1 = d_in[15];
  const void* wn2  = d_in[16]; const void* bn2 = d_in[17];
  const void* fcnw = d_in[18]; const void* fcnb = d_in[19];
  const void* f3w  = d_in[20]; const void* f3b  = d_in[21];

  char* ws = (char*)d_ws;
  ushort* xT = (ushort*)(ws);                // 14,745,600 B
  ushort* h0 = (ushort*)(ws + 14745600);     //  7,372,800 B
  ushort* h1 = (ushort*)(ws + 22118400);     //  3,686,400 B
  ushort* h2 = (ushort*)(ws + 25804800);     //  1,843,200 B
  float* y   = (float*)(ws + 27648000);      //      4,096 B
  int* flags = (int*)(ws + 27652096);        //  flags[0..1], flags[16]=done ctr

  transpose_kernel<<<dim3(450, 4), 256, 0, stream>>>(x, knn0, xT, y, flags);

  lcn_layer<<<dim3(1800, 2), 256, 0, stream>>>(xT, knn0, wp0, bp0, wn0, bn0, h0,
                                               flags, 14400, 7200);
  lcn_layer<<<dim3(900, 2), 256, 0, stream>>>(h0, knn1, wp1, bp1, wn1, bn1, h1,
                                              flags, 7200, 3600);
  lcn_layer<<<dim3(450, 2), 256, 0, stream>>>(h1, knn2, wp2, bp2, wn2, bn2, h2,
                                              flags, 3600, 1800);

  fc_final_kernel<<<113, 256, 0, stream>>>(h2, fcpw, fcnw, fcpb, fcnb, f3w, f3b,
                                           y, flags, d_out);
}

// Round 6
// 178.185 us; speedup vs baseline: 2.2615x; 1.0168x over previous
//
#include <hip/hip_runtime.h>
#include <hip/hip_bf16.h>

using bf16 = __hip_bfloat16;

#define K 25
#define B 256

__device__ __forceinline__ float b2f(ushort u) {
  unsigned int w = ((unsigned int)u) << 16;
  float f; __builtin_memcpy(&f, &w, 4); return f;
}
__device__ __forceinline__ ushort f2b(float f) {
  bf16 h = __float2bfloat16(f);
  ushort u; __builtin_memcpy(&u, &h, 2); return u;
}

// ---------------------------------------------------------------------------
// Transpose x (256 x 28800) -> xT (28800 x 256 bf16), 64x64 tiles, vectorized.
// grid (450, 4). Dtype detect done with 2 parallel gather loads + ballot.
// Block (0,0): publishes flags, zeros y + fc done-counter.
// fdt=1 -> float tensors bf16, 0 -> fp32. idt=1 -> knn int64, 0 -> int32.
// ---------------------------------------------------------------------------
__global__ __launch_bounds__(256) void transpose_kernel(const void* __restrict__ x,
                                                        const void* __restrict__ knn0,
                                                        ushort* __restrict__ xT,
                                                        float* __restrict__ y,
                                                        int* __restrict__ flags) {
  __shared__ float tile[64][65];
  __shared__ int s_flags[2];
  const int t = threadIdx.x;

  // wave 0: fp32-vs-bf16 vote (N(0,1) fp32 exponents never land outside (30,192))
  if (t < 64) {
    const unsigned int u = ((const unsigned int*)x)[t * 997];
    const unsigned int e = (u >> 23) & 0xFF;
    const unsigned long long m = __ballot((e >= 192) || (e <= 30));
    if (t == 0) s_flags[0] = (__popcll(m) >= 32) ? 1 : 0;
  } else if (t < 128) {
    // wave 1: int64-vs-int32 vote (odd 32-bit words all zero <=> int64)
    const int l = t - 64;
    const unsigned int hi = ((const unsigned int*)knn0)[2 * l + 1];
    const unsigned long long m = __ballot(hi != 0);
    if (l == 0) s_flags[1] = (m == 0ULL) ? 1 : 0;
  }
  __syncthreads();
  const int fdt = s_flags[0];

  if (blockIdx.x == 0 && blockIdx.y == 0) {
    if (t == 0) {
      flags[0] = s_flags[0];
      flags[1] = s_flags[1];
      flags[16] = 0;                        // fc done-counter
    }
#pragma unroll
    for (int i = 0; i < 4; ++i) y[t + i * 256] = 0.0f;
  }

  const int f0 = blockIdx.x * 64;
  const int b0 = blockIdx.y * 64;
  if (fdt) {
    const ushort* xp = (const ushort*)x;
#pragma unroll
    for (int q = 0; q < 4; ++q) {
      const int lin = t + q * 256;
      const int bl = lin >> 4;
      const int fq = (lin & 15) << 2;
      const ushort4 v = *(const ushort4*)(xp + (size_t)(b0 + bl) * 28800 + f0 + fq);
      tile[bl][fq] = b2f(v.x); tile[bl][fq + 1] = b2f(v.y);
      tile[bl][fq + 2] = b2f(v.z); tile[bl][fq + 3] = b2f(v.w);
    }
  } else {
    const float* xp = (const float*)x;
#pragma unroll
    for (int q = 0; q < 4; ++q) {
      const int lin = t + q * 256;
      const int bl = lin >> 4;
      const int fq = (lin & 15) << 2;
      const float4 v = *(const float4*)(xp + (size_t)(b0 + bl) * 28800 + f0 + fq);
      tile[bl][fq] = v.x; tile[bl][fq + 1] = v.y;
      tile[bl][fq + 2] = v.z; tile[bl][fq + 3] = v.w;
    }
  }
  __syncthreads();
#pragma unroll
  for (int q = 0; q < 4; ++q) {
    const int lin = t + q * 256;
    const int fl = lin >> 4;
    const int bq = (lin & 15) << 2;
    ushort4 o;
    o.x = f2b(tile[bq][fl]);     o.y = f2b(tile[bq + 1][fl]);
    o.z = f2b(tile[bq + 2][fl]); o.w = f2b(tile[bq + 3][fl]);
    *(ushort4*)(xT + (size_t)(f0 + fl) * B + b0 + bq) = o;
  }
}

// ---------------------------------------------------------------------------
// One LCN layer, both channels, batch split in halves for XCD-L2 locality.
// Wave-task = (dim d, channel ch, batch-half): lane reads ushort2 (256 B/row
// segment, coalesced). blockIdx.x & 3 selects (ch, half) so that with the
// round-robin block->XCD mapping (%8) each (ch,half) is pinned to XCD pair
// {cf, cf+4}: per-XCD gather working set = prev*256 B (<= 3.68 MB) fits the
// 4 MiB L2, and h-layer writes land in the same XCDs that read them next.
// grid (dout) blocks of 256: d = (blockIdx>>2)*4 + wave.
// ---------------------------------------------------------------------------
__global__ __launch_bounds__(256) void lcn_layer(const ushort* __restrict__ inT,
                                                 const void* __restrict__ knn,
                                                 const void* __restrict__ wp,
                                                 const void* __restrict__ bp,
                                                 const void* __restrict__ wn,
                                                 const void* __restrict__ bn,
                                                 ushort* __restrict__ outT,
                                                 const int* __restrict__ flags,
                                                 int prev, int dout) {
  const int fdt = flags[0];
  const int idt = flags[1];
  const int wave = threadIdx.x >> 6;
  const int lane = threadIdx.x & 63;
  const int cf   = blockIdx.x & 3;
  const int ch   = cf >> 1;
  const int half = cf & 1;
  const int d    = (blockIdx.x >> 2) * 4 + wave;

  const ushort* in = inT + (size_t)ch * prev * B + half * 128;
  const void* wsel = ch ? wn : wp;
  const void* bsel = ch ? bn : bp;

  int r[K]; float wk[K];
  if (idt) {
    const long long* ip = (const long long*)knn + (size_t)d * K;
#pragma unroll
    for (int k = 0; k < K; ++k) r[k] = (int)ip[k];
  } else {
    const int* ip = (const int*)knn + (size_t)d * K;
#pragma unroll
    for (int k = 0; k < K; ++k) r[k] = ip[k];
  }
  if (fdt) {
    const ushort* wpp = (const ushort*)wsel + (size_t)d * K;
#pragma unroll
    for (int k = 0; k < K; ++k) wk[k] = b2f(wpp[k]);
  } else {
    const float* wpp = (const float*)wsel + (size_t)d * K;
#pragma unroll
    for (int k = 0; k < K; ++k) wk[k] = wpp[k];
  }
  const float bias = fdt ? b2f(((const ushort*)bsel)[d]) : ((const float*)bsel)[d];

  float a0 = 0.f, a1 = 0.f;
#pragma unroll
  for (int k = 0; k < K; ++k) {
    const ushort2 v = *(const ushort2*)(in + (size_t)r[k] * B + (lane << 1));
    a0 = fmaf(wk[k], b2f(v.x), a0);
    a1 = fmaf(wk[k], b2f(v.y), a1);
  }
  a0 = fmaxf(a0 + bias, 0.f);
  a1 = fmaxf(a1 + bias, 0.f);
  ushort2 o; o.x = f2b(a0); o.y = f2b(a1);
  *(ushort2*)(outT + ((size_t)ch * dout + d) * B + half * 128 + (lane << 1)) = o;
}

// ---------------------------------------------------------------------------
// fc (wave-tasked, atomics into zeroed y) + fused final combine (last block).
// grid 113 blocks x 256. 450 wave-tasks of 8 dims each.
// ---------------------------------------------------------------------------
__global__ __launch_bounds__(256) void fc_final_kernel(const ushort* __restrict__ h2,
                                                       const void* __restrict__ fcpw,
                                                       const void* __restrict__ fcnw,
                                                       const void* __restrict__ fcpb,
                                                       const void* __restrict__ fcnb,
                                                       const void* __restrict__ f3w,
                                                       const void* __restrict__ f3b,
                                                       float* __restrict__ y,
                                                       int* __restrict__ flags,
                                                       void* __restrict__ out) {
  const int fdt = flags[0];
  const int wave = threadIdx.x >> 6;
  const int lane = threadIdx.x & 63;
  const int wt = blockIdx.x * 4 + wave;
  __shared__ int s_last;

  if (wt < 450) {
    const int ch = wt >= 225;
    const int c0 = (ch ? wt - 225 : wt) * 8;
    const ushort* h = h2 + (size_t)ch * 1800 * B;
    const void* fw = ch ? fcnw : fcpw;
    float w0[8], w1[8];
    if (fdt) {
      const ushort* fp = (const ushort*)fw;
#pragma unroll
      for (int j = 0; j < 8; ++j) { w0[j] = b2f(fp[c0 + j]); w1[j] = b2f(fp[1800 + c0 + j]); }
    } else {
      const float* fp = (const float*)fw;
#pragma unroll
      for (int j = 0; j < 8; ++j) { w0[j] = fp[c0 + j]; w1[j] = fp[1800 + c0 + j]; }
    }
    float s0[4] = {0.f, 0.f, 0.f, 0.f}, s1[4] = {0.f, 0.f, 0.f, 0.f};
#pragma unroll
    for (int j = 0; j < 8; ++j) {
      const ushort4 v = *(const ushort4*)(h + (size_t)(c0 + j) * B + (lane << 2));
      const float f0v = b2f(v.x), f1v = b2f(v.y), f2v = b2f(v.z), f3v = b2f(v.w);
      s0[0] = fmaf(w0[j], f0v, s0[0]); s0[1] = fmaf(w0[j], f1v, s0[1]);
      s0[2] = fmaf(w0[j], f2v, s0[2]); s0[3] = fmaf(w0[j], f3v, s0[3]);
      s1[0] = fmaf(w1[j], f0v, s1[0]); s1[1] = fmaf(w1[j], f1v, s1[1]);
      s1[2] = fmaf(w1[j], f2v, s1[2]); s1[3] = fmaf(w1[j], f3v, s1[3]);
    }
#pragma unroll
    for (int i = 0; i < 4; ++i) {
      atomicAdd(&y[(ch * 2 + 0) * B + (lane << 2) + i], s0[i]);
      atomicAdd(&y[(ch * 2 + 1) * B + (lane << 2) + i], s1[i]);
    }
  }

  __syncthreads();
  if (threadIdx.x == 0) {
    __threadfence();
    s_last = (atomicAdd(&flags[16], 1) == gridDim.x - 1);
  }
  __syncthreads();
  if (s_last) {
    const int b = threadIdx.x;
    const float y0 = atomicAdd(&y[0 * B + b], 0.0f);
    const float y1 = atomicAdd(&y[1 * B + b], 0.0f);
    const float y2 = atomicAdd(&y[2 * B + b], 0.0f);
    const float y3 = atomicAdd(&y[3 * B + b], 0.0f);
    const float bp0v = fdt ? b2f(((const ushort*)fcpb)[0]) : ((const float*)fcpb)[0];
    const float bp1v = fdt ? b2f(((const ushort*)fcpb)[1]) : ((const float*)fcpb)[1];
    const float bn0v = fdt ? b2f(((const ushort*)fcnb)[0]) : ((const float*)fcnb)[0];
    const float bn1v = fdt ? b2f(((const ushort*)fcnb)[1]) : ((const float*)fcnb)[1];
    const float h0v = fmaxf(y0 + bp0v, 0.f);
    const float h1v = fmaxf(y1 + bp1v, 0.f);
    const float h2v = fmaxf(y2 + bn0v, 0.f);
    const float h3v = fmaxf(y3 + bn1v, 0.f);
#pragma unroll
    for (int o = 0; o < 2; ++o) {
      float w0, w1, w2, w3, bb;
      if (fdt) {
        const ushort* fp = (const ushort*)f3w;
        w0 = b2f(fp[o * 4 + 0]); w1 = b2f(fp[o * 4 + 1]);
        w2 = b2f(fp[o * 4 + 2]); w3 = b2f(fp[o * 4 + 3]);
        bb = b2f(((const ushort*)f3b)[o]);
      } else {
        const float* fp = (const float*)f3w;
        w0 = fp[o * 4 + 0]; w1 = fp[o * 4 + 1];
        w2 = fp[o * 4 + 2]; w3 = fp[o * 4 + 3];
        bb = ((const float*)f3b)[o];
      }
      float r = bb;
      r = fmaf(w0, h0v, r); r = fmaf(w1, h1v, r);
      r = fmaf(w2, h2v, r); r = fmaf(w3, h3v, r);
      if (fdt) ((ushort*)out)[b * 2 + o] = f2b(r);
      else     ((float*)out)[b * 2 + o] = r;
    }
  }
}

extern "C" void kernel_launch(void* const* d_in, const int* in_sizes, int n_in,
                              void* d_out, int out_size, void* d_ws, size_t ws_size,
                              hipStream_t stream) {
  const void* x    = d_in[0];
  const void* knn0 = d_in[1];
  const void* knn1 = d_in[2];
  const void* knn2 = d_in[3];
  const void* wp0  = d_in[4];  const void* bp0 = d_in[5];
  const void* wp1  = d_in[6];  const void* bp1 = d_in[7];
  const void* wp2  = d_in[8];  const void* bp2 = d_in[9];
  const void* fcpw = d_in[10]; const void* fcpb = d_in[11];
  const void* wn0  = d_in[12]; const void* bn0 = d_in[13];
  const void* wn1  = d_in[14]; const void* bn1 = d_in[15];
  const void* wn2  = d_in[16]; const void* bn2 = d_in[17];
  const void* fcnw = d_in[18]; const void* fcnb = d_in[19];
  const void* f3w  = d_in[20]; const void* f3b  = d_in[21];

  char* ws = (char*)d_ws;
  ushort* xT = (ushort*)(ws);                // 14,745,600 B
  ushort* h0 = (ushort*)(ws + 14745600);     //  7,372,800 B
  ushort* h1 = (ushort*)(ws + 22118400);     //  3,686,400 B
  ushort* h2 = (ushort*)(ws + 25804800);     //  1,843,200 B
  float* y   = (float*)(ws + 27648000);      //      4,096 B
  int* flags = (int*)(ws + 27652096);        //  flags[0..1], flags[16]=done ctr

  transpose_kernel<<<dim3(450, 4), 256, 0, stream>>>(x, knn0, xT, y, flags);

  lcn_layer<<<7200, 256, 0, stream>>>(xT, knn0, wp0, bp0, wn0, bn0, h0,
                                      flags, 14400, 7200);
  lcn_layer<<<3600, 256, 0, stream>>>(h0, knn1, wp1, bp1, wn1, bn1, h1,
                                      flags, 7200, 3600);
  lcn_layer<<<1800, 256, 0, stream>>>(h1, knn2, wp2, bp2, wn2, bn2, h2,
                                      flags, 3600, 1800);

  fc_final_kernel<<<113, 256, 0, stream>>>(h2, fcpw, fcnw, fcpb, fcnb, f3w, f3b,
                                           y, flags, d_out);
}

// Round 7
// 174.250 us; speedup vs baseline: 2.3126x; 1.0226x over previous
//
#include <hip/hip_runtime.h>
#include <hip/hip_bf16.h>

using bf16 = __hip_bfloat16;

#define K 25
#define D0 7200
#define D1 3600
#define D2 1800

// pk stream word bases: [L0ch0][L0ch1][L1ch0][L1ch1][L2ch0][L2ch1], layout [k][d]
#define PKB_L1 360000
#define PKB_L2 540000
#define NPK    630000
// pbias bases
#define PBB_L1 14400
#define PBB_L2 21600
#define NPB    25200

__device__ __forceinline__ float b2f(ushort u) {
  unsigned int w = ((unsigned int)u) << 16;
  float f; __builtin_memcpy(&f, &w, 4); return f;
}
__device__ __forceinline__ ushort f2b(float f) {
  bf16 h = __float2bfloat16(f);
  ushort u; __builtin_memcpy(&u, &h, 2); return u;
}

// ---------------------------------------------------------------------------
// Prepack: detect dtypes (validated votes), normalize indices+weights into a
// uint32 stream pk[(L,ch)][k][d] = (idx16 << 16) | bf16(w[d][k]), biases into
// fp32 pbias, zero y accumulators, init flags. One dispatch, ~2.6 MB writes.
// ---------------------------------------------------------------------------
__global__ __launch_bounds__(256) void prepack_kernel(
    const void* __restrict__ x,
    const void* __restrict__ knn0, const void* __restrict__ knn1,
    const void* __restrict__ knn2,
    const void* __restrict__ wp0, const void* __restrict__ bp0,
    const void* __restrict__ wp1, const void* __restrict__ bp1,
    const void* __restrict__ wp2, const void* __restrict__ bp2,
    const void* __restrict__ wn0, const void* __restrict__ bn0,
    const void* __restrict__ wn1, const void* __restrict__ bn1,
    const void* __restrict__ wn2, const void* __restrict__ bn2,
    unsigned int* __restrict__ pk, float* __restrict__ pbias,
    float* __restrict__ y, int* __restrict__ flags) {
  __shared__ int s_flags[2];
  const int t = threadIdx.x;
  // fdt=1 -> floats are bf16; idt=1 -> knn is int64
  if (t < 64) {
    const unsigned int u = ((const unsigned int*)x)[t * 997];
    const unsigned int e = (u >> 23) & 0xFF;
    const unsigned long long m = __ballot((e >= 192) || (e <= 30));
    if (t == 0) s_flags[0] = (__popcll(m) >= 32) ? 1 : 0;
  } else if (t < 128) {
    const int l = t - 64;
    const unsigned int hi = ((const unsigned int*)knn0)[2 * l + 1];
    const unsigned long long m = __ballot(hi != 0);
    if (l == 0) s_flags[1] = (m == 0ULL) ? 1 : 0;
  }
  __syncthreads();
  const int fdt = s_flags[0], idt = s_flags[1];

  if (blockIdx.x == 0 && t == 0) {
    flags[0] = fdt; flags[1] = idt; flags[16] = 0;
  }

  const int gid = blockIdx.x * 256 + t;
  if (gid < NPK) {
    int i = gid, ch, k, d, dout;
    const void *kn, *wsel;
    if (i < PKB_L1) {
      ch = i / 180000; i -= ch * 180000; dout = D0; kn = knn0;
      wsel = ch ? wn0 : wp0;
    } else if (i < PKB_L2) {
      i -= PKB_L1; ch = i / 90000; i -= ch * 90000; dout = D1; kn = knn1;
      wsel = ch ? wn1 : wp1;
    } else {
      i -= PKB_L2; ch = i / 45000; i -= ch * 45000; dout = D2; kn = knn2;
      wsel = ch ? wn2 : wp2;
    }
    k = i / dout; d = i - k * dout;
    const int pos = d * K + k;
    const unsigned int idx = idt ? ((const unsigned int*)kn)[2 * pos]
                                 : ((const unsigned int*)kn)[pos];
    const ushort wb = fdt ? ((const ushort*)wsel)[pos]
                          : f2b(((const float*)wsel)[pos]);
    pk[gid] = (idx << 16) | (unsigned int)wb;
  } else if (gid < NPK + NPB) {
    int i = gid - NPK, ch, d;
    const void* src;
    if (i < PBB_L1) {
      ch = i / D0; d = i - ch * D0; src = ch ? bn0 : bp0;
    } else if (i < PBB_L2) {
      const int i2 = i - PBB_L1; ch = i2 / D1; d = i2 - ch * D1; src = ch ? bn1 : bp1;
    } else {
      const int i2 = i - PBB_L2; ch = i2 / D2; d = i2 - ch * D2; src = ch ? bn2 : bp2;
    }
    pbias[i] = fdt ? b2f(((const ushort*)src)[d]) : ((const float*)src)[d];
  } else if (gid < NPK + NPB + 1024) {
    y[gid - (NPK + NPB)] = 0.0f;
  }
}

// ---------------------------------------------------------------------------
// One LCN layer inside LDS: out[d][0..1] = relu(sum_k w * in[idx][0..1] + b)
// lds holds activations as [f][2] bf16 pairs (one uint per feature).
// pk layout [k][d]: lanes (consecutive d) load coalesced per k.
// ---------------------------------------------------------------------------
__device__ __forceinline__ void layer_run(ushort* lds, const unsigned int* __restrict__ pk,
                                          const float* __restrict__ pbias,
                                          int offIn, int offOut, int pkb, int pbb,
                                          int dout) {
  for (int d = threadIdx.x; d < dout; d += 256) {
    const unsigned int* s = pk + pkb + d;
    float a0 = 0.f, a1 = 0.f;
#pragma unroll
    for (int k = 0; k < K; ++k) {
      const unsigned int pw = s[k * dout];
      const unsigned int vv = *(const unsigned int*)&lds[offIn + ((pw >> 16) << 1)];
      const float w = b2f((ushort)(pw & 0xFFFFu));
      a0 = fmaf(w, b2f((ushort)(vv & 0xFFFFu)), a0);
      a1 = fmaf(w, b2f((ushort)(vv >> 16)), a1);
    }
    const float bias = pbias[pbb + d];
    a0 = fmaxf(a0 + bias, 0.f);
    a1 = fmaxf(a1 + bias, 0.f);
    *(unsigned int*)&lds[offOut + (d << 1)] =
        (unsigned int)f2b(a0) | ((unsigned int)f2b(a1) << 16);
  }
}

// ---------------------------------------------------------------------------
// Fused network: block = (channel, batch-slice of 2). Stages the input slice
// in LDS, runs all 3 LCN layers + fc with only __syncthreads between stages.
// LDS plan (ushort idx): L0: in@0(28800) -> h0@28800(14400);
// L1: h0@28800 -> h1@0(7200); L2: h1@0 -> h2@7200(3600); fc reads h2@7200.
// grid 256 x 256 threads (1 block/CU, LDS 86.4 KB caps at 1 anyway).
// ---------------------------------------------------------------------------
__global__ __launch_bounds__(256) void lcn_fused(
    const void* __restrict__ x, const unsigned int* __restrict__ pk,
    const float* __restrict__ pbias,
    const void* __restrict__ fcpw, const void* __restrict__ fcnw,
    const void* __restrict__ fcpb, const void* __restrict__ fcnb,
    const void* __restrict__ f3w, const void* __restrict__ f3b,
    float* __restrict__ y, int* __restrict__ flags, void* __restrict__ out) {
  __shared__ ushort lds[43200];      // 86,400 B
  __shared__ float red[4][4];
  __shared__ int sflag;
  const int t = threadIdx.x;
  const int ch = blockIdx.x & 1;
  const int b0 = (blockIdx.x >> 1) * 2;

  if (t == 0) sflag = flags[0];
  __syncthreads();
  const int fdt = sflag;

  // ---- stage input rows b0, b0+1 (this channel's 14400 features) ----
  if (fdt) {
    const ushort* r0 = (const ushort*)x + (size_t)b0 * 28800 + ch * 14400;
    const ushort* r1 = r0 + 28800;
    for (int c = t; c < 3600; c += 256) {
      const ushort4 a = ((const ushort4*)r0)[c];
      const ushort4 b = ((const ushort4*)r1)[c];
      unsigned int* dst = (unsigned int*)&lds[c * 8];
      dst[0] = (unsigned int)a.x | ((unsigned int)b.x << 16);
      dst[1] = (unsigned int)a.y | ((unsigned int)b.y << 16);
      dst[2] = (unsigned int)a.z | ((unsigned int)b.z << 16);
      dst[3] = (unsigned int)a.w | ((unsigned int)b.w << 16);
    }
  } else {
    const float* r0 = (const float*)x + (size_t)b0 * 28800 + ch * 14400;
    const float* r1 = r0 + 28800;
    for (int c = t; c < 3600; c += 256) {
      const float4 a = ((const float4*)r0)[c];
      const float4 b = ((const float4*)r1)[c];
      unsigned int* dst = (unsigned int*)&lds[c * 8];
      dst[0] = (unsigned int)f2b(a.x) | ((unsigned int)f2b(b.x) << 16);
      dst[1] = (unsigned int)f2b(a.y) | ((unsigned int)f2b(b.y) << 16);
      dst[2] = (unsigned int)f2b(a.z) | ((unsigned int)f2b(b.z) << 16);
      dst[3] = (unsigned int)f2b(a.w) | ((unsigned int)f2b(b.w) << 16);
    }
  }
  __syncthreads();

  layer_run(lds, pk, pbias, 0, 28800, 0 + ch * 180000, 0 + ch * D0, D0);
  __syncthreads();
  layer_run(lds, pk, pbias, 28800, 0, PKB_L1 + ch * 90000, PBB_L1 + ch * D1, D1);
  __syncthreads();
  layer_run(lds, pk, pbias, 0, 7200, PKB_L2 + ch * 45000, PBB_L2 + ch * D2, D2);
  __syncthreads();

  // ---- fc: y[ch][o][b0..b0+1] = sum_d fw[o][d] * h2[d][.] ----
  {
    const void* fw = ch ? fcnw : fcpw;
    float a00 = 0.f, a01 = 0.f, a10 = 0.f, a11 = 0.f;
    for (int d = t; d < D2; d += 256) {
      const unsigned int vv = *(const unsigned int*)&lds[7200 + (d << 1)];
      const float v0 = b2f((ushort)(vv & 0xFFFFu));
      const float v1 = b2f((ushort)(vv >> 16));
      const float w0 = fdt ? b2f(((const ushort*)fw)[d]) : ((const float*)fw)[d];
      const float w1 = fdt ? b2f(((const ushort*)fw)[D2 + d]) : ((const float*)fw)[D2 + d];
      a00 = fmaf(w0, v0, a00); a01 = fmaf(w0, v1, a01);
      a10 = fmaf(w1, v0, a10); a11 = fmaf(w1, v1, a11);
    }
#pragma unroll
    for (int off = 32; off > 0; off >>= 1) {
      a00 += __shfl_down(a00, off);
      a01 += __shfl_down(a01, off);
      a10 += __shfl_down(a10, off);
      a11 += __shfl_down(a11, off);
    }
    const int wave = t >> 6, lane = t & 63;
    if (lane == 0) {
      red[wave][0] = a00; red[wave][1] = a01; red[wave][2] = a10; red[wave][3] = a11;
    }
    __syncthreads();
    if (t == 0) {
      const float s00 = red[0][0] + red[1][0] + red[2][0] + red[3][0];
      const float s01 = red[0][1] + red[1][1] + red[2][1] + red[3][1];
      const float s10 = red[0][2] + red[1][2] + red[2][2] + red[3][2];
      const float s11 = red[0][3] + red[1][3] + red[2][3] + red[3][3];
      atomicAdd(&y[(ch * 2 + 0) * 256 + b0], s00);
      atomicAdd(&y[(ch * 2 + 0) * 256 + b0 + 1], s01);
      atomicAdd(&y[(ch * 2 + 1) * 256 + b0], s10);
      atomicAdd(&y[(ch * 2 + 1) * 256 + b0 + 1], s11);
    }
  }

  // ---- last-done block computes the final combine (round-5-validated) ----
  __syncthreads();
  if (t == 0) {
    __threadfence();
    sflag = (atomicAdd(&flags[16], 1) == (int)gridDim.x - 1) ? 1 : 0;
  }
  __syncthreads();
  if (sflag) {
    const int b = t;
    const float y0 = atomicAdd(&y[0 * 256 + b], 0.0f);
    const float y1 = atomicAdd(&y[1 * 256 + b], 0.0f);
    const float y2 = atomicAdd(&y[2 * 256 + b], 0.0f);
    const float y3 = atomicAdd(&y[3 * 256 + b], 0.0f);
    const float bp0v = fdt ? b2f(((const ushort*)fcpb)[0]) : ((const float*)fcpb)[0];
    const float bp1v = fdt ? b2f(((const ushort*)fcpb)[1]) : ((const float*)fcpb)[1];
    const float bn0v = fdt ? b2f(((const ushort*)fcnb)[0]) : ((const float*)fcnb)[0];
    const float bn1v = fdt ? b2f(((const ushort*)fcnb)[1]) : ((const float*)fcnb)[1];
    const float h0v = fmaxf(y0 + bp0v, 0.f);
    const float h1v = fmaxf(y1 + bp1v, 0.f);
    const float h2v = fmaxf(y2 + bn0v, 0.f);
    const float h3v = fmaxf(y3 + bn1v, 0.f);
#pragma unroll
    for (int o = 0; o < 2; ++o) {
      float w0, w1, w2, w3, bb;
      if (fdt) {
        const ushort* fp = (const ushort*)f3w;
        w0 = b2f(fp[o * 4 + 0]); w1 = b2f(fp[o * 4 + 1]);
        w2 = b2f(fp[o * 4 + 2]); w3 = b2f(fp[o * 4 + 3]);
        bb = b2f(((const ushort*)f3b)[o]);
      } else {
        const float* fp = (const float*)f3w;
        w0 = fp[o * 4 + 0]; w1 = fp[o * 4 + 1];
        w2 = fp[o * 4 + 2]; w3 = fp[o * 4 + 3];
        bb = ((const float*)f3b)[o];
      }
      float r = bb;
      r = fmaf(w0, h0v, r); r = fmaf(w1, h1v, r);
      r = fmaf(w2, h2v, r); r = fmaf(w3, h3v, r);
      if (fdt) ((ushort*)out)[b * 2 + o] = f2b(r);
      else     ((float*)out)[b * 2 + o] = r;
    }
  }
}

extern "C" void kernel_launch(void* const* d_in, const int* in_sizes, int n_in,
                              void* d_out, int out_size, void* d_ws, size_t ws_size,
                              hipStream_t stream) {
  const void* x    = d_in[0];
  const void* knn0 = d_in[1];
  const void* knn1 = d_in[2];
  const void* knn2 = d_in[3];
  const void* wp0  = d_in[4];  const void* bp0 = d_in[5];
  const void* wp1  = d_in[6];  const void* bp1 = d_in[7];
  const void* wp2  = d_in[8];  const void* bp2 = d_in[9];
  const void* fcpw = d_in[10]; const void* fcpb = d_in[11];
  const void* wn0  = d_in[12]; const void* bn0 = d_in[13];
  const void* wn1  = d_in[14]; const void* bn1 = d_in[15];
  const void* wn2  = d_in[16]; const void* bn2 = d_in[17];
  const void* fcnw = d_in[18]; const void* fcnb = d_in[19];
  const void* f3w  = d_in[20]; const void* f3b  = d_in[21];

  char* ws = (char*)d_ws;
  unsigned int* pk = (unsigned int*)(ws);        // 630000*4 = 2,520,000 B
  float* pbias = (float*)(ws + 2520000);          // 25200*4  =   100,800 B
  float* y     = (float*)(ws + 2620800);          // 1024*4   =     4,096 B
  int* flags   = (int*)(ws + 2624896);            // flags[0..1], flags[16]

  // items: 630000 pk + 25200 bias + 1024 y-zero = 656224 -> 2564 blocks
  prepack_kernel<<<2564, 256, 0, stream>>>(x, knn0, knn1, knn2,
                                           wp0, bp0, wp1, bp1, wp2, bp2,
                                           wn0, bn0, wn1, bn1, wn2, bn2,
                                           pk, pbias, y, flags);

  lcn_fused<<<256, 256, 0, stream>>>(x, pk, pbias, fcpw, fcnw, fcpb, fcnb,
                                     f3w, f3b, y, flags, d_out);
}

// Round 8
// 152.049 us; speedup vs baseline: 2.6503x; 1.1460x over previous
//
#include <hip/hip_runtime.h>
#include <hip/hip_bf16.h>

using bf16 = __hip_bfloat16;

#define K 25
#define D0 7200
#define D1 3600
#define D2 1800

// pk stream word bases: [L0ch0][L0ch1][L1ch0][L1ch1][L2ch0][L2ch1], layout [k][d]
#define PKB_L1 360000
#define PKB_L2 540000
#define NPK    630000
// pbias bases
#define PBB_L1 14400
#define PBB_L2 21600
#define NPB    25200

#define NT 512   // threads per fused block (8 waves/CU; LDS caps blocks/CU at 1)

__device__ __forceinline__ float b2f(ushort u) {
  unsigned int w = ((unsigned int)u) << 16;
  float f; __builtin_memcpy(&f, &w, 4); return f;
}
__device__ __forceinline__ ushort f2b(float f) {
  bf16 h = __float2bfloat16(f);
  ushort u; __builtin_memcpy(&u, &h, 2); return u;
}

// ---------------------------------------------------------------------------
// Prepack: detect dtypes (validated votes), normalize indices+weights into a
// uint32 stream pk[(L,ch)][k][d] = (idx16 << 16) | bf16(w[d][k]), biases into
// fp32 pbias, zero y accumulators, init flags.
// ---------------------------------------------------------------------------
__global__ __launch_bounds__(256) void prepack_kernel(
    const void* __restrict__ x,
    const void* __restrict__ knn0, const void* __restrict__ knn1,
    const void* __restrict__ knn2,
    const void* __restrict__ wp0, const void* __restrict__ bp0,
    const void* __restrict__ wp1, const void* __restrict__ bp1,
    const void* __restrict__ wp2, const void* __restrict__ bp2,
    const void* __restrict__ wn0, const void* __restrict__ bn0,
    const void* __restrict__ wn1, const void* __restrict__ bn1,
    const void* __restrict__ wn2, const void* __restrict__ bn2,
    unsigned int* __restrict__ pk, float* __restrict__ pbias,
    float* __restrict__ y, int* __restrict__ flags) {
  __shared__ int s_flags[2];
  const int t = threadIdx.x;
  // fdt=1 -> floats are bf16; idt=1 -> knn is int64
  if (t < 64) {
    const unsigned int u = ((const unsigned int*)x)[t * 997];
    const unsigned int e = (u >> 23) & 0xFF;
    const unsigned long long m = __ballot((e >= 192) || (e <= 30));
    if (t == 0) s_flags[0] = (__popcll(m) >= 32) ? 1 : 0;
  } else if (t < 128) {
    const int l = t - 64;
    const unsigned int hi = ((const unsigned int*)knn0)[2 * l + 1];
    const unsigned long long m = __ballot(hi != 0);
    if (l == 0) s_flags[1] = (m == 0ULL) ? 1 : 0;
  }
  __syncthreads();
  const int fdt = s_flags[0], idt = s_flags[1];

  if (blockIdx.x == 0 && t == 0) {
    flags[0] = fdt; flags[1] = idt; flags[16] = 0;
  }

  const int gid = blockIdx.x * 256 + t;
  if (gid < NPK) {
    int i = gid, ch, k, d, dout;
    const void *kn, *wsel;
    if (i < PKB_L1) {
      ch = i / 180000; i -= ch * 180000; dout = D0; kn = knn0;
      wsel = ch ? wn0 : wp0;
    } else if (i < PKB_L2) {
      i -= PKB_L1; ch = i / 90000; i -= ch * 90000; dout = D1; kn = knn1;
      wsel = ch ? wn1 : wp1;
    } else {
      i -= PKB_L2; ch = i / 45000; i -= ch * 45000; dout = D2; kn = knn2;
      wsel = ch ? wn2 : wp2;
    }
    k = i / dout; d = i - k * dout;
    const int pos = d * K + k;
    const unsigned int idx = idt ? ((const unsigned int*)kn)[2 * pos]
                                 : ((const unsigned int*)kn)[pos];
    const ushort wb = fdt ? ((const ushort*)wsel)[pos]
                          : f2b(((const float*)wsel)[pos]);
    pk[gid] = (idx << 16) | (unsigned int)wb;
  } else if (gid < NPK + NPB) {
    int i = gid - NPK, ch, d;
    const void* src;
    if (i < PBB_L1) {
      ch = i / D0; d = i - ch * D0; src = ch ? bn0 : bp0;
    } else if (i < PBB_L2) {
      const int i2 = i - PBB_L1; ch = i2 / D1; d = i2 - ch * D1; src = ch ? bn1 : bp1;
    } else {
      const int i2 = i - PBB_L2; ch = i2 / D2; d = i2 - ch * D2; src = ch ? bn2 : bp2;
    }
    pbias[i] = fdt ? b2f(((const ushort*)src)[d]) : ((const float*)src)[d];
  } else if (gid < NPK + NPB + 1024) {
    y[gid - (NPK + NPB)] = 0.0f;
  }
}

// ---------------------------------------------------------------------------
// One LCN layer inside LDS: out[d][0..1] = relu(sum_k w * in[idx][0..1] + b)
// lds holds activations as [f][2] bf16 pairs (one uint per feature).
// pk layout [k][d]: lanes (consecutive d) load coalesced per k.
// ---------------------------------------------------------------------------
__device__ __forceinline__ void layer_run(ushort* lds, const unsigned int* __restrict__ pk,
                                          const float* __restrict__ pbias,
                                          int offIn, int offOut, int pkb, int pbb,
                                          int dout) {
  for (int d = threadIdx.x; d < dout; d += NT) {
    const unsigned int* s = pk + pkb + d;
    float a0 = 0.f, a1 = 0.f;
#pragma unroll
    for (int k = 0; k < K; ++k) {
      const unsigned int pw = s[k * dout];
      const unsigned int vv = *(const unsigned int*)&lds[offIn + ((pw >> 16) << 1)];
      const float w = b2f((ushort)(pw & 0xFFFFu));
      a0 = fmaf(w, b2f((ushort)(vv & 0xFFFFu)), a0);
      a1 = fmaf(w, b2f((ushort)(vv >> 16)), a1);
    }
    const float bias = pbias[pbb + d];
    a0 = fmaxf(a0 + bias, 0.f);
    a1 = fmaxf(a1 + bias, 0.f);
    *(unsigned int*)&lds[offOut + (d << 1)] =
        (unsigned int)f2b(a0) | ((unsigned int)f2b(a1) << 16);
  }
}

// ---------------------------------------------------------------------------
// Fused network: block = (channel, batch-slice of 2), NT=512 threads (8 waves)
// to hide LDS gather latency (LDS 86.4 KB -> 1 block/CU regardless).
// LDS plan (ushort idx): L0: in@0(28800) -> h0@28800(14400);
// L1: h0@28800 -> h1@0(7200); L2: h1@0 -> h2@7200(3600); fc reads h2@7200.
// ---------------------------------------------------------------------------
__global__ __launch_bounds__(NT) void lcn_fused(
    const void* __restrict__ x, const unsigned int* __restrict__ pk,
    const float* __restrict__ pbias,
    const void* __restrict__ fcpw, const void* __restrict__ fcnw,
    const void* __restrict__ fcpb, const void* __restrict__ fcnb,
    const void* __restrict__ f3w, const void* __restrict__ f3b,
    float* __restrict__ y, int* __restrict__ flags, void* __restrict__ out) {
  __shared__ ushort lds[43200];      // 86,400 B
  __shared__ float red[NT / 64][4];
  __shared__ int sflag;
  const int t = threadIdx.x;
  const int ch = blockIdx.x & 1;
  const int b0 = (blockIdx.x >> 1) * 2;

  if (t == 0) sflag = flags[0];
  __syncthreads();
  const int fdt = sflag;

  // ---- stage input rows b0, b0+1 (this channel's 14400 features) ----
  if (fdt) {
    const ushort* r0 = (const ushort*)x + (size_t)b0 * 28800 + ch * 14400;
    const ushort* r1 = r0 + 28800;
    for (int c = t; c < 3600; c += NT) {
      const ushort4 a = ((const ushort4*)r0)[c];
      const ushort4 b = ((const ushort4*)r1)[c];
      unsigned int* dst = (unsigned int*)&lds[c * 8];
      dst[0] = (unsigned int)a.x | ((unsigned int)b.x << 16);
      dst[1] = (unsigned int)a.y | ((unsigned int)b.y << 16);
      dst[2] = (unsigned int)a.z | ((unsigned int)b.z << 16);
      dst[3] = (unsigned int)a.w | ((unsigned int)b.w << 16);
    }
  } else {
    const float* r0 = (const float*)x + (size_t)b0 * 28800 + ch * 14400;
    const float* r1 = r0 + 28800;
    for (int c = t; c < 3600; c += NT) {
      const float4 a = ((const float4*)r0)[c];
      const float4 b = ((const float4*)r1)[c];
      unsigned int* dst = (unsigned int*)&lds[c * 8];
      dst[0] = (unsigned int)f2b(a.x) | ((unsigned int)f2b(b.x) << 16);
      dst[1] = (unsigned int)f2b(a.y) | ((unsigned int)f2b(b.y) << 16);
      dst[2] = (unsigned int)f2b(a.z) | ((unsigned int)f2b(b.z) << 16);
      dst[3] = (unsigned int)f2b(a.w) | ((unsigned int)f2b(b.w) << 16);
    }
  }
  __syncthreads();

  layer_run(lds, pk, pbias, 0, 28800, 0 + ch * 180000, 0 + ch * D0, D0);
  __syncthreads();
  layer_run(lds, pk, pbias, 28800, 0, PKB_L1 + ch * 90000, PBB_L1 + ch * D1, D1);
  __syncthreads();
  layer_run(lds, pk, pbias, 0, 7200, PKB_L2 + ch * 45000, PBB_L2 + ch * D2, D2);
  __syncthreads();

  // ---- fc: y[ch][o][b0..b0+1] = sum_d fw[o][d] * h2[d][.] ----
  {
    const void* fw = ch ? fcnw : fcpw;
    float a00 = 0.f, a01 = 0.f, a10 = 0.f, a11 = 0.f;
    for (int d = t; d < D2; d += NT) {
      const unsigned int vv = *(const unsigned int*)&lds[7200 + (d << 1)];
      const float v0 = b2f((ushort)(vv & 0xFFFFu));
      const float v1 = b2f((ushort)(vv >> 16));
      const float w0 = fdt ? b2f(((const ushort*)fw)[d]) : ((const float*)fw)[d];
      const float w1 = fdt ? b2f(((const ushort*)fw)[D2 + d]) : ((const float*)fw)[D2 + d];
      a00 = fmaf(w0, v0, a00); a01 = fmaf(w0, v1, a01);
      a10 = fmaf(w1, v0, a10); a11 = fmaf(w1, v1, a11);
    }
#pragma unroll
    for (int off = 32; off > 0; off >>= 1) {
      a00 += __shfl_down(a00, off);
      a01 += __shfl_down(a01, off);
      a10 += __shfl_down(a10, off);
      a11 += __shfl_down(a11, off);
    }
    const int wave = t >> 6, lane = t & 63;
    if (lane == 0) {
      red[wave][0] = a00; red[wave][1] = a01; red[wave][2] = a10; red[wave][3] = a11;
    }
    __syncthreads();
    if (t == 0) {
      float s00 = 0.f, s01 = 0.f, s10 = 0.f, s11 = 0.f;
#pragma unroll
      for (int wv = 0; wv < NT / 64; ++wv) {
        s00 += red[wv][0]; s01 += red[wv][1]; s10 += red[wv][2]; s11 += red[wv][3];
      }
      atomicAdd(&y[(ch * 2 + 0) * 256 + b0], s00);
      atomicAdd(&y[(ch * 2 + 0) * 256 + b0 + 1], s01);
      atomicAdd(&y[(ch * 2 + 1) * 256 + b0], s10);
      atomicAdd(&y[(ch * 2 + 1) * 256 + b0 + 1], s11);
    }
  }

  // ---- last-done block computes the final combine (round-5-validated) ----
  __syncthreads();
  if (t == 0) {
    __threadfence();
    sflag = (atomicAdd(&flags[16], 1) == (int)gridDim.x - 1) ? 1 : 0;
  }
  __syncthreads();
  if (sflag && t < 256) {
    const int b = t;
    const float y0 = atomicAdd(&y[0 * 256 + b], 0.0f);
    const float y1 = atomicAdd(&y[1 * 256 + b], 0.0f);
    const float y2 = atomicAdd(&y[2 * 256 + b], 0.0f);
    const float y3 = atomicAdd(&y[3 * 256 + b], 0.0f);
    const float bp0v = fdt ? b2f(((const ushort*)fcpb)[0]) : ((const float*)fcpb)[0];
    const float bp1v = fdt ? b2f(((const ushort*)fcpb)[1]) : ((const float*)fcpb)[1];
    const float bn0v = fdt ? b2f(((const ushort*)fcnb)[0]) : ((const float*)fcnb)[0];
    const float bn1v = fdt ? b2f(((const ushort*)fcnb)[1]) : ((const float*)fcnb)[1];
    const float h0v = fmaxf(y0 + bp0v, 0.f);
    const float h1v = fmaxf(y1 + bp1v, 0.f);
    const float h2v = fmaxf(y2 + bn0v, 0.f);
    const float h3v = fmaxf(y3 + bn1v, 0.f);
#pragma unroll
    for (int o = 0; o < 2; ++o) {
      float w0, w1, w2, w3, bb;
      if (fdt) {
        const ushort* fp = (const ushort*)f3w;
        w0 = b2f(fp[o * 4 + 0]); w1 = b2f(fp[o * 4 + 1]);
        w2 = b2f(fp[o * 4 + 2]); w3 = b2f(fp[o * 4 + 3]);
        bb = b2f(((const ushort*)f3b)[o]);
      } else {
        const float* fp = (const float*)f3w;
        w0 = fp[o * 4 + 0]; w1 = fp[o * 4 + 1];
        w2 = fp[o * 4 + 2]; w3 = fp[o * 4 + 3];
        bb = ((const float*)f3b)[o];
      }
      float r = bb;
      r = fmaf(w0, h0v, r); r = fmaf(w1, h1v, r);
      r = fmaf(w2, h2v, r); r = fmaf(w3, h3v, r);
      if (fdt) ((ushort*)out)[b * 2 + o] = f2b(r);
      else     ((float*)out)[b * 2 + o] = r;
    }
  }
}

extern "C" void kernel_launch(void* const* d_in, const int* in_sizes, int n_in,
                              void* d_out, int out_size, void* d_ws, size_t ws_size,
                              hipStream_t stream) {
  const void* x    = d_in[0];
  const void* knn0 = d_in[1];
  const void* knn1 = d_in[2];
  const void* knn2 = d_in[3];
  const void* wp0  = d_in[4];  const void* bp0 = d_in[5];
  const void* wp1  = d_in[6];  const void* bp1 = d_in[7];
  const void* wp2  = d_in[8];  const void* bp2 = d_in[9];
  const void* fcpw = d_in[10]; const void* fcpb = d_in[11];
  const void* wn0  = d_in[12]; const void* bn0 = d_in[13];
  const void* wn1  = d_in[14]; const void* bn1 = d_in[15];
  const void* wn2  = d_in[16]; const void* bn2 = d_in[17];
  const void* fcnw = d_in[18]; const void* fcnb = d_in[19];
  const void* f3w  = d_in[20]; const void* f3b  = d_in[21];

  char* ws = (char*)d_ws;
  unsigned int* pk = (unsigned int*)(ws);         // 630000*4 = 2,520,000 B
  float* pbias = (float*)(ws + 2520000);          // 25200*4  =   100,800 B
  float* y     = (float*)(ws + 2620800);          // 1024*4   =     4,096 B
  int* flags   = (int*)(ws + 2624896);            // flags[0..1], flags[16]

  // items: 630000 pk + 25200 bias + 1024 y-zero = 656224 -> 2564 blocks
  prepack_kernel<<<2564, 256, 0, stream>>>(x, knn0, knn1, knn2,
                                           wp0, bp0, wp1, bp1, wp2, bp2,
                                           wn0, bn0, wn1, bn1, wn2, bn2,
                                           pk, pbias, y, flags);

  lcn_fused<<<256, NT, 0, stream>>>(x, pk, pbias, fcpw, fcnw, fcpb, fcnb,
                                    f3w, f3b, y, flags, d_out);
}

// Round 9
// 147.821 us; speedup vs baseline: 2.7261x; 1.0286x over previous
//
#include <hip/hip_runtime.h>
#include <hip/hip_bf16.h>

using bf16 = __hip_bfloat16;

#define K 25
#define D0 7200
#define D1 3600
#define D2 1800

// pk stream word bases: [L0ch0][L0ch1][L1ch0][L1ch1][L2ch0][L2ch1], layout [k][d]
#define PKB_L1 360000
#define PKB_L2 540000
#define NPK    630000
// pbias layout: [L0ch0][L0ch1][L1ch0][L1ch1][L2ch0][L2ch1] (25200 entries)
#define NPB    25200

#define NT 1024  // threads per fused block (16 waves/CU; LDS caps blocks/CU at 1)

__device__ __forceinline__ float b2f(ushort u) {
  unsigned int w = ((unsigned int)u) << 16;
  float f; __builtin_memcpy(&f, &w, 4); return f;
}
__device__ __forceinline__ ushort f2b(float f) {
  bf16 h = __float2bfloat16(f);
  ushort u; __builtin_memcpy(&u, &h, 2); return u;
}

// ---------------------------------------------------------------------------
// Prepack, one thread per output dim (25200 dims): reads 25 contiguous
// idx/w entries, writes pk[k*dout+d] lane-coalesced. Also fp32 biases,
// y zeroing, flags. Dtype votes (validated r2-r8) per block.
// ---------------------------------------------------------------------------
__global__ __launch_bounds__(256) void prepack_kernel(
    const void* __restrict__ x,
    const void* __restrict__ knn0, const void* __restrict__ knn1,
    const void* __restrict__ knn2,
    const void* __restrict__ wp0, const void* __restrict__ bp0,
    const void* __restrict__ wp1, const void* __restrict__ bp1,
    const void* __restrict__ wp2, const void* __restrict__ bp2,
    const void* __restrict__ wn0, const void* __restrict__ bn0,
    const void* __restrict__ wn1, const void* __restrict__ bn1,
    const void* __restrict__ wn2, const void* __restrict__ bn2,
    unsigned int* __restrict__ pk, float* __restrict__ pbias,
    float* __restrict__ y, int* __restrict__ flags) {
  __shared__ int s_flags[2];
  const int t = threadIdx.x;
  // fdt=1 -> floats are bf16; idt=1 -> knn is int64
  if (t < 64) {
    const unsigned int u = ((const unsigned int*)x)[t * 997];
    const unsigned int e = (u >> 23) & 0xFF;
    const unsigned long long m = __ballot((e >= 192) || (e <= 30));
    if (t == 0) s_flags[0] = (__popcll(m) >= 32) ? 1 : 0;
  } else if (t < 128) {
    const int l = t - 64;
    const unsigned int hi = ((const unsigned int*)knn0)[2 * l + 1];
    const unsigned long long m = __ballot(hi != 0);
    if (l == 0) s_flags[1] = (m == 0ULL) ? 1 : 0;
  }
  __syncthreads();
  const int fdt = s_flags[0], idt = s_flags[1];

  if (blockIdx.x == 0 && t == 0) {
    flags[0] = fdt; flags[1] = idt; flags[16] = 0;
  }

  const int gid = blockIdx.x * 256 + t;
  if (gid < NPB) {
    // map gid -> (layer, ch, d)
    int i = gid, d, dout, pkb;
    const void *kn, *wsel, *bsel;
    if (i < 14400) {
      const int ch = i / D0; d = i - ch * D0; dout = D0;
      pkb = ch * 180000; kn = knn0;
      wsel = ch ? wn0 : wp0; bsel = ch ? bn0 : bp0;
    } else if (i < 21600) {
      i -= 14400; const int ch = i / D1; d = i - ch * D1; dout = D1;
      pkb = PKB_L1 + ch * 90000; kn = knn1;
      wsel = ch ? wn1 : wp1; bsel = ch ? bn1 : bp1;
    } else {
      i -= 21600; const int ch = i / D2; d = i - ch * D2; dout = D2;
      pkb = PKB_L2 + ch * 45000; kn = knn2;
      wsel = ch ? wn2 : wp2; bsel = ch ? bn2 : bp2;
    }
    const int pos0 = d * K;
#pragma unroll
    for (int k = 0; k < K; ++k) {
      const unsigned int idx = idt ? ((const unsigned int*)kn)[2 * (pos0 + k)]
                                   : ((const unsigned int*)kn)[pos0 + k];
      const ushort wb = fdt ? ((const ushort*)wsel)[pos0 + k]
                            : f2b(((const float*)wsel)[pos0 + k]);
      pk[pkb + k * dout + d] = (idx << 16) | (unsigned int)wb;
    }
    pbias[gid] = fdt ? b2f(((const ushort*)bsel)[d]) : ((const float*)bsel)[d];
  } else if (gid < NPB + 1024) {
    y[gid - NPB] = 0.0f;
  }
}

// ---------------------------------------------------------------------------
// One LCN layer inside LDS: out[d][0..1] = relu(sum_k w * in[idx][0..1] + b)
// lds holds activations as [f][2] bf16 pairs (one uint per feature).
// pk layout [k][d]: lanes (consecutive d) load coalesced per k.
// ---------------------------------------------------------------------------
__device__ __forceinline__ void layer_run(ushort* lds, const unsigned int* __restrict__ pk,
                                          const float* __restrict__ pbias,
                                          int offIn, int offOut, int pkb, int pbb,
                                          int dout) {
  for (int d = threadIdx.x; d < dout; d += NT) {
    const unsigned int* s = pk + pkb + d;
    float a0 = 0.f, a1 = 0.f;
#pragma unroll
    for (int k = 0; k < K; ++k) {
      const unsigned int pw = s[k * dout];
      const unsigned int vv = *(const unsigned int*)&lds[offIn + ((pw >> 16) << 1)];
      const float w = b2f((ushort)(pw & 0xFFFFu));
      a0 = fmaf(w, b2f((ushort)(vv & 0xFFFFu)), a0);
      a1 = fmaf(w, b2f((ushort)(vv >> 16)), a1);
    }
    const float bias = pbias[pbb + d];
    a0 = fmaxf(a0 + bias, 0.f);
    a1 = fmaxf(a1 + bias, 0.f);
    *(unsigned int*)&lds[offOut + (d << 1)] =
        (unsigned int)f2b(a0) | ((unsigned int)f2b(a1) << 16);
  }
}

// ---------------------------------------------------------------------------
// Fused network: block = (channel, batch-slice of 2), NT=1024 (16 waves/CU)
// to hide LDS gather latency (LDS 86.4 KB -> 1 block/CU regardless).
// LDS plan (ushort idx): L0: in@0(28800) -> h0@28800(14400);
// L1: h0@28800 -> h1@0(7200); L2: h1@0 -> h2@7200(3600); fc reads h2@7200.
// ---------------------------------------------------------------------------
__global__ __launch_bounds__(NT) void lcn_fused(
    const void* __restrict__ x, const unsigned int* __restrict__ pk,
    const float* __restrict__ pbias,
    const void* __restrict__ fcpw, const void* __restrict__ fcnw,
    const void* __restrict__ fcpb, const void* __restrict__ fcnb,
    const void* __restrict__ f3w, const void* __restrict__ f3b,
    float* __restrict__ y, int* __restrict__ flags, void* __restrict__ out) {
  __shared__ ushort lds[43200];      // 86,400 B
  __shared__ float red[NT / 64][4];
  __shared__ int sflag;
  const int t = threadIdx.x;
  const int ch = blockIdx.x & 1;
  const int b0 = (blockIdx.x >> 1) * 2;

  if (t == 0) sflag = flags[0];
  __syncthreads();
  const int fdt = sflag;

  // ---- stage input rows b0, b0+1 (this channel's 14400 features) ----
  if (fdt) {
    const ushort* r0 = (const ushort*)x + (size_t)b0 * 28800 + ch * 14400;
    const ushort* r1 = r0 + 28800;
    for (int c = t; c < 3600; c += NT) {
      const ushort4 a = ((const ushort4*)r0)[c];
      const ushort4 b = ((const ushort4*)r1)[c];
      unsigned int* dst = (unsigned int*)&lds[c * 8];
      dst[0] = (unsigned int)a.x | ((unsigned int)b.x << 16);
      dst[1] = (unsigned int)a.y | ((unsigned int)b.y << 16);
      dst[2] = (unsigned int)a.z | ((unsigned int)b.z << 16);
      dst[3] = (unsigned int)a.w | ((unsigned int)b.w << 16);
    }
  } else {
    const float* r0 = (const float*)x + (size_t)b0 * 28800 + ch * 14400;
    const float* r1 = r0 + 28800;
    for (int c = t; c < 3600; c += NT) {
      const float4 a = ((const float4*)r0)[c];
      const float4 b = ((const float4*)r1)[c];
      unsigned int* dst = (unsigned int*)&lds[c * 8];
      dst[0] = (unsigned int)f2b(a.x) | ((unsigned int)f2b(b.x) << 16);
      dst[1] = (unsigned int)f2b(a.y) | ((unsigned int)f2b(b.y) << 16);
      dst[2] = (unsigned int)f2b(a.z) | ((unsigned int)f2b(b.z) << 16);
      dst[3] = (unsigned int)f2b(a.w) | ((unsigned int)f2b(b.w) << 16);
    }
  }
  __syncthreads();

  layer_run(lds, pk, pbias, 0, 28800, 0 + ch * 180000, 0 + ch * D0, D0);
  __syncthreads();
  layer_run(lds, pk, pbias, 28800, 0, PKB_L1 + ch * 90000, 14400 + ch * D1, D1);
  __syncthreads();
  layer_run(lds, pk, pbias, 0, 7200, PKB_L2 + ch * 45000, 21600 + ch * D2, D2);
  __syncthreads();

  // ---- fc: y[ch][o][b0..b0+1] = sum_d fw[o][d] * h2[d][.] ----
  {
    const void* fw = ch ? fcnw : fcpw;
    float a00 = 0.f, a01 = 0.f, a10 = 0.f, a11 = 0.f;
    for (int d = t; d < D2; d += NT) {
      const unsigned int vv = *(const unsigned int*)&lds[7200 + (d << 1)];
      const float v0 = b2f((ushort)(vv & 0xFFFFu));
      const float v1 = b2f((ushort)(vv >> 16));
      const float w0 = fdt ? b2f(((const ushort*)fw)[d]) : ((const float*)fw)[d];
      const float w1 = fdt ? b2f(((const ushort*)fw)[D2 + d]) : ((const float*)fw)[D2 + d];
      a00 = fmaf(w0, v0, a00); a01 = fmaf(w0, v1, a01);
      a10 = fmaf(w1, v0, a10); a11 = fmaf(w1, v1, a11);
    }
#pragma unroll
    for (int off = 32; off > 0; off >>= 1) {
      a00 += __shfl_down(a00, off);
      a01 += __shfl_down(a01, off);
      a10 += __shfl_down(a10, off);
      a11 += __shfl_down(a11, off);
    }
    const int wave = t >> 6, lane = t & 63;
    if (lane == 0) {
      red[wave][0] = a00; red[wave][1] = a01; red[wave][2] = a10; red[wave][3] = a11;
    }
    __syncthreads();
    if (t == 0) {
      float s00 = 0.f, s01 = 0.f, s10 = 0.f, s11 = 0.f;
#pragma unroll
      for (int wv = 0; wv < NT / 64; ++wv) {
        s00 += red[wv][0]; s01 += red[wv][1]; s10 += red[wv][2]; s11 += red[wv][3];
      }
      atomicAdd(&y[(ch * 2 + 0) * 256 + b0], s00);
      atomicAdd(&y[(ch * 2 + 0) * 256 + b0 + 1], s01);
      atomicAdd(&y[(ch * 2 + 1) * 256 + b0], s10);
      atomicAdd(&y[(ch * 2 + 1) * 256 + b0 + 1], s11);
    }
  }

  // ---- last-done block computes the final combine (round-5-validated) ----
  __syncthreads();
  if (t == 0) {
    __threadfence();
    sflag = (atomicAdd(&flags[16], 1) == (int)gridDim.x - 1) ? 1 : 0;
  }
  __syncthreads();
  if (sflag && t < 256) {
    const int b = t;
    const float y0 = atomicAdd(&y[0 * 256 + b], 0.0f);
    const float y1 = atomicAdd(&y[1 * 256 + b], 0.0f);
    const float y2 = atomicAdd(&y[2 * 256 + b], 0.0f);
    const float y3 = atomicAdd(&y[3 * 256 + b], 0.0f);
    const float bp0v = fdt ? b2f(((const ushort*)fcpb)[0]) : ((const float*)fcpb)[0];
    const float bp1v = fdt ? b2f(((const ushort*)fcpb)[1]) : ((const float*)fcpb)[1];
    const float bn0v = fdt ? b2f(((const ushort*)fcnb)[0]) : ((const float*)fcnb)[0];
    const float bn1v = fdt ? b2f(((const ushort*)fcnb)[1]) : ((const float*)fcnb)[1];
    const float h0v = fmaxf(y0 + bp0v, 0.f);
    const float h1v = fmaxf(y1 + bp1v, 0.f);
    const float h2v = fmaxf(y2 + bn0v, 0.f);
    const float h3v = fmaxf(y3 + bn1v, 0.f);
#pragma unroll
    for (int o = 0; o < 2; ++o) {
      float w0, w1, w2, w3, bb;
      if (fdt) {
        const ushort* fp = (const ushort*)f3w;
        w0 = b2f(fp[o * 4 + 0]); w1 = b2f(fp[o * 4 + 1]);
        w2 = b2f(fp[o * 4 + 2]); w3 = b2f(fp[o * 4 + 3]);
        bb = b2f(((const ushort*)f3b)[o]);
      } else {
        const float* fp = (const float*)f3w;
        w0 = fp[o * 4 + 0]; w1 = fp[o * 4 + 1];
        w2 = fp[o * 4 + 2]; w3 = fp[o * 4 + 3];
        bb = ((const float*)f3b)[o];
      }
      float r = bb;
      r = fmaf(w0, h0v, r); r = fmaf(w1, h1v, r);
      r = fmaf(w2, h2v, r); r = fmaf(w3, h3v, r);
      if (fdt) ((ushort*)out)[b * 2 + o] = f2b(r);
      else     ((float*)out)[b * 2 + o] = r;
    }
  }
}

extern "C" void kernel_launch(void* const* d_in, const int* in_sizes, int n_in,
                              void* d_out, int out_size, void* d_ws, size_t ws_size,
                              hipStream_t stream) {
  const void* x    = d_in[0];
  const void* knn0 = d_in[1];
  const void* knn1 = d_in[2];
  const void* knn2 = d_in[3];
  const void* wp0  = d_in[4];  const void* bp0 = d_in[5];
  const void* wp1  = d_in[6];  const void* bp1 = d_in[7];
  const void* wp2  = d_in[8];  const void* bp2 = d_in[9];
  const void* fcpw = d_in[10]; const void* fcpb = d_in[11];
  const void* wn0  = d_in[12]; const void* bn0 = d_in[13];
  const void* wn1  = d_in[14]; const void* bn1 = d_in[15];
  const void* wn2  = d_in[16]; const void* bn2 = d_in[17];
  const void* fcnw = d_in[18]; const void* fcnb = d_in[19];
  const void* f3w  = d_in[20]; const void* f3b  = d_in[21];

  char* ws = (char*)d_ws;
  unsigned int* pk = (unsigned int*)(ws);         // 630000*4 = 2,520,000 B
  float* pbias = (float*)(ws + 2520000);          // 25200*4  =   100,800 B
  float* y     = (float*)(ws + 2620800);          // 1024*4   =     4,096 B
  int* flags   = (int*)(ws + 2624896);            // flags[0..1], flags[16]

  // tasks: 25200 dims + 1024 y-zero = 26224 -> 103 blocks of 256
  prepack_kernel<<<103, 256, 0, stream>>>(x, knn0, knn1, knn2,
                                          wp0, bp0, wp1, bp1, wp2, bp2,
                                          wn0, bn0, wn1, bn1, wn2, bn2,
                                          pk, pbias, y, flags);

  lcn_fused<<<256, NT, 0, stream>>>(x, pk, pbias, fcpw, fcnw, fcpb, fcnb,
                                    f3w, f3b, y, flags, d_out);
}